// Round 11
// baseline (406.075 us; speedup 1.0000x reference)
//
#include <hip/hip_runtime.h>
#include <hip/hip_bf16.h>
#include <math.h>

typedef __hip_bfloat16 bf16;

#define BB 4
#define NN 4096
#define KNB 10
#define KQ 16            // queries per KNN block (held in pinned VGPRs)
#define KCAP 64          // survivor capacity per query

typedef __bf16 bfv8 __attribute__((ext_vector_type(8)));
typedef float  f32x4 __attribute__((ext_vector_type(4)));

__device__ __forceinline__ float ldT(const float* p) { return *p; }
__device__ __forceinline__ float ldT(const bf16* p)  { return __bfloat162float(*p); }
__device__ __forceinline__ void  stT(float* p, float v) { *p = v; }
__device__ __forceinline__ void  stT(bf16* p,  float v) { *p = __float2bfloat16(v); }

__device__ __forceinline__ unsigned short f2us(float x) {
  union { bf16 h; unsigned short u; } cv;
  cv.h = __float2bfloat16(x);
  return cv.u;
}

// load 8 consecutive elements as bf16 bit patterns (vector fast path)
__device__ __forceinline__ void ld8bits(const float* p, unsigned short* s) {
  const float4 a = *(const float4*)p;
  const float4 b = *(const float4*)(p + 4);
  s[0] = f2us(a.x); s[1] = f2us(a.y); s[2] = f2us(a.z); s[3] = f2us(a.w);
  s[4] = f2us(b.x); s[5] = f2us(b.y); s[6] = f2us(b.z); s[7] = f2us(b.w);
}
__device__ __forceinline__ void ld8bits(const bf16* p, unsigned short* s) {
  const uint2 a = *(const uint2*)p;        // 8B-aligned for all row strides used here
  const uint2 b = *(const uint2*)(p + 4);
  s[0] = a.x & 0xffff; s[1] = a.x >> 16; s[2] = a.y & 0xffff; s[3] = a.y >> 16;
  s[4] = b.x & 0xffff; s[5] = b.x >> 16; s[6] = b.y & 0xffff; s[7] = b.y >> 16;
}

__device__ __forceinline__ bfv8 ldfrag(const unsigned short* p) {
  union { uint4 u; bfv8 v; } t;
  t.u = *(const uint4*)p;
  return t.v;
}

// ---------- dtype sniffer (fallback when in_sizes is inconclusive) ----------
__global__ void k_sniff(const unsigned int* __restrict__ pcw, int* __restrict__ flag) {
  if (blockIdx.x == 0 && threadIdx.x == 0) {
    int hits = 0;
    for (int i = 0; i < 64; ++i) {
      unsigned int e = (pcw[i] >> 7) & 0xFF;
      if (e >= 100 && e <= 140) ++hits;
    }
    *flag = (hits >= 40) ? 1 : 0;   // 1 = bf16 I/O, 0 = fp32 I/O
  }
}

// ---------- prep: xyz fp32 + packed {x,y,z,norm} + out0 copy ----------
template <class TI, class TO>
__global__ void k_prep(const int* __restrict__ flag, int want,
                       const TI* __restrict__ pc, float* __restrict__ xyz,
                       float4* __restrict__ pts4, TO* __restrict__ out0) {
  if (flag && *flag != want) return;
  int i = blockIdx.x * blockDim.x + threadIdx.x;
  if (i >= BB * NN) return;
  float x = ldT(pc + i * 3 + 0), y = ldT(pc + i * 3 + 1), z = ldT(pc + i * 3 + 2);
  xyz[i * 3 + 0] = x; xyz[i * 3 + 1] = y; xyz[i * 3 + 2] = z;
  // norm with the same fmaf chain k_knn uses -> identical distances
  const float nrm = fmaf(x, x, fmaf(y, y, z * z));
  pts4[i] = make_float4(x, y, z, nrm);
  stT(out0 + i * 3 + 0, x); stT(out0 + i * 3 + 1, y); stT(out0 + i * 3 + 2, z);
}

// ---------- h1 -> out2 copy + fbuf rows 0..127, vectorized 8 elems/thread ----------
// bf16 mode: pure bit-copies (uint4 in, 2x uint4 out). fp32 mode: 2x float4 in,
// 2x float4 out + packed bf16 uint4. (G13: scalar bf16 loads are 2-2.5x slower.)
template <class TI, class TO>
__global__ void k_h1(const int* __restrict__ flag, int want,
                     const TI* __restrict__ h1, TO* __restrict__ out2,
                     bf16* __restrict__ fbuf) {
  if (flag && *flag != want) return;
  const int per8 = 128 * NN / 8;               // 8-elem groups per batch
  int g = blockIdx.x * blockDim.x + threadIdx.x;
  if (g >= BB * per8) return;
  const int b = g / per8;
  const int e = (g - b * per8) * 8;            // element offset within batch
  const size_t src = (size_t)b * (128 * NN) + e;
  bf16* fb = fbuf + (size_t)b * 160 * NN + e;
  if constexpr (sizeof(TI) == 2) {
    const uint4 u = *(const uint4*)(h1 + src);
    *(uint4*)(out2 + src) = u;
    *(uint4*)fb = u;
  } else {
    const float4 a = *(const float4*)(h1 + src);
    const float4 c = *(const float4*)(h1 + src + 4);
    *(float4*)(out2 + src) = a;
    *(float4*)(out2 + src + 4) = c;
    uint4 u;
    u.x = (unsigned)f2us(a.x) | ((unsigned)f2us(a.y) << 16);
    u.y = (unsigned)f2us(a.z) | ((unsigned)f2us(a.w) << 16);
    u.z = (unsigned)f2us(c.x) | ((unsigned)f2us(c.y) << 16);
    u.w = (unsigned)f2us(c.z) | ((unsigned)f2us(c.w) << 16);
    *(uint4*)fb = u;
  }
}

// ---------- KNN v11 (R9 best, unchanged): candidate-major, 16 queries pinned ----------
__global__ __launch_bounds__(256, 4) void k_knn(const float4* __restrict__ pts4,
                                                int* __restrict__ idxout) {
  __shared__ float smin[256][KQ + 1];   // stride 17 dw: 2 lanes/bank = free
  __shared__ float stau[KQ];
  __shared__ float sd[KQ][KCAP];
  __shared__ int   si[KQ][KCAP];
  __shared__ unsigned int scnt[KQ];
  const int tid = threadIdx.x;
  const int b = blockIdx.y;
  const int nBase = blockIdx.x * KQ;
  const float4* pb = pts4 + (size_t)b * NN;
  if (tid < KQ) scnt[tid] = 0u;

  // query coords: global -> registers, PINNED so the compiler can't sink them
  float qx[KQ], qy[KQ], qz[KQ], qn[KQ];
  #pragma unroll
  for (int q = 0; q < KQ; ++q) {
    const float4 p = pb[nBase + q];
    qx[q] = p.x; qy[q] = p.y; qz[q] = p.z; qn[q] = p.w;
  }
  #pragma unroll
  for (int q = 0; q < KQ; ++q)
    asm volatile("" : "+v"(qx[q]), "+v"(qy[q]), "+v"(qz[q]), "+v"(qn[q]));

  // ---- phase 1: per-thread min over 16 coalesced candidates x 16 queries
  float mv[KQ];
  #pragma unroll
  for (int q = 0; q < KQ; ++q) mv[q] = 1e30f;
  {
    float4 cA = pb[tid];
    #pragma unroll
    for (int it = 0; it < 16; ++it) {
      const float4 cB = (it + 1 < 16) ? pb[(it + 1) * 256 + tid] : cA;  // 2-deep prefetch
      #pragma unroll
      for (int q = 0; q < KQ; ++q) {
        const float dot = fmaf(qx[q], cA.x, fmaf(qy[q], cA.y, qz[q] * cA.z));
        const float d = (qn[q] + cA.w) - 2.0f * dot;
        mv[q] = fminf(mv[q], d);
      }
      cA = cB;
    }
  }
  #pragma unroll
  for (int q = 0; q < KQ; ++q) smin[tid][q] = mv[q];
  __syncthreads();

  // ---- tau: thread q scans the 256 minima for query q, keeps 10 smallest
  if (tid < KQ) {
    float arr[KNB];
    #pragma unroll
    for (int t = 0; t < KNB; ++t) arr[t] = 1e30f;
    for (int t = 0; t < 256; ++t) {
      const float v = smin[t][tid];
      if (v < arr[KNB - 1]) {
        arr[KNB - 1] = v;
        #pragma unroll
        for (int u = KNB - 1; u > 0; --u)
          if (arr[u] < arr[u - 1]) { const float tm = arr[u]; arr[u] = arr[u - 1]; arr[u - 1] = tm; }
      }
    }
    stau[tid] = arr[KNB - 1];
  }
  __syncthreads();
  float tq[KQ];
  #pragma unroll
  for (int q = 0; q < KQ; ++q) tq[q] = stau[q];

  // ---- phase 2: rescan (L1-hot), filter, push survivors
  {
    float4 cA = pb[tid];
    #pragma unroll
    for (int it = 0; it < 16; ++it) {
      const float4 cB = (it + 1 < 16) ? pb[(it + 1) * 256 + tid] : cA;
      const int j = it * 256 + tid;
      #pragma unroll
      for (int q = 0; q < KQ; ++q) {
        const float dot = fmaf(qx[q], cA.x, fmaf(qy[q], cA.y, qz[q] * cA.z));
        const float d = (qn[q] + cA.w) - 2.0f * dot;
        if (d <= tq[q]) {
          const unsigned int pos = atomicAdd(&scnt[q], 1u);
          if (pos < KCAP) { sd[q][pos] = d; si[q][pos] = j; }
        }
      }
      cA = cB;
    }
  }
  __syncthreads();

  // ---- phase 3: exact lex (d, idx) top-10 over survivors; thread q = query q
  if (tid < KQ) {
    const int qq = tid;
    const int nq = nBase + qq;
    int* op = idxout + ((size_t)b * NN + nq) * KNB;
    const unsigned int m = scnt[qq];
    float dk[KNB]; int ik[KNB];
    #pragma unroll
    for (int t = 0; t < KNB; ++t) { dk[t] = 1e30f; ik[t] = NN; }
    if (m <= KCAP) {
      for (unsigned int e = 0; e < m; ++e) {
        const float d = sd[qq][e];
        const int j = si[qq][e];
        if (d < dk[KNB - 1] || (d == dk[KNB - 1] && j < ik[KNB - 1])) {
          dk[KNB - 1] = d; ik[KNB - 1] = j;
          #pragma unroll
          for (int t = KNB - 1; t > 0; --t) {
            if (dk[t] < dk[t - 1] || (dk[t] == dk[t - 1] && ik[t] < ik[t - 1])) {
              const float td = dk[t]; dk[t] = dk[t - 1]; dk[t - 1] = td;
              const int ti = ik[t]; ik[t] = ik[t - 1]; ik[t - 1] = ti;
            }
          }
        }
      }
    } else {
      // exact serial fallback (correctness insurance; never taken for random data)
      const float4 pQ = pb[nq];
      for (int j = 0; j < NN; ++j) {
        const float4 c = pb[j];
        const float dot = fmaf(pQ.x, c.x, fmaf(pQ.y, c.y, pQ.z * c.z));
        const float d = (pQ.w + c.w) - 2.0f * dot;
        if (d < dk[KNB - 1] || (d == dk[KNB - 1] && j < ik[KNB - 1])) {
          dk[KNB - 1] = d; ik[KNB - 1] = j;
          #pragma unroll
          for (int t = KNB - 1; t > 0; --t) {
            if (dk[t] < dk[t - 1] || (dk[t] == dk[t - 1] && ik[t] < ik[t - 1])) {
              const float td = dk[t]; dk[t] = dk[t - 1]; dk[t - 1] = td;
              const int ti = ik[t]; ik[t] = ik[t - 1]; ik[t - 1] = ti;
            }
          }
        }
      }
    }
    #pragma unroll
    for (int t = 0; t < KNB; ++t) op[t] = ik[t];
  }
}

// ---------- eigen features ----------
template <class TP, class TO>
__global__ void k_ef(const int* __restrict__ flag, int want,
                     const float* __restrict__ xyz, const int* __restrict__ idxin,
                     const TP* __restrict__ W1, const TP* __restrict__ b1,
                     const TP* __restrict__ W2, const TP* __restrict__ b2,
                     TO* __restrict__ out4, bf16* __restrict__ zbuf) {
  if (flag && *flag != want) return;
  int i = blockIdx.x * blockDim.x + threadIdx.x;
  if (i >= BB * NN) return;
  int b = i / NN, n = i - b * NN;
  const float* xb = xyz + (size_t)b * NN * 3;
  const int* id = idxin + (size_t)i * KNB;
  double px[KNB], py[KNB], pz[KNB];
  double mx = 0, my = 0, mz = 0;
  #pragma unroll
  for (int k = 0; k < KNB; ++k) {
    int j = id[k];
    px[k] = (double)xb[j * 3 + 0];
    py[k] = (double)xb[j * 3 + 1];
    pz[k] = (double)xb[j * 3 + 2];
    mx += px[k]; my += py[k]; mz += pz[k];
  }
  mx /= KNB; my /= KNB; mz /= KNB;
  double c00 = 0, c01 = 0, c02 = 0, c11 = 0, c12 = 0, c22 = 0;
  #pragma unroll
  for (int k = 0; k < KNB; ++k) {
    double dx = px[k] - mx, dy = py[k] - my, dz = pz[k] - mz;
    c00 += dx * dx; c01 += dx * dy; c02 += dx * dz;
    c11 += dy * dy; c12 += dy * dz; c22 += dz * dz;
  }
  c00 /= KNB; c01 /= KNB; c02 /= KNB; c11 /= KNB; c12 /= KNB; c22 /= KNB;
  double e0, e1, e2;
  {
    double p1 = c01 * c01 + c02 * c02 + c12 * c12;
    double q = (c00 + c11 + c22) / 3.0;
    double d0 = c00 - q, d1 = c11 - q, d2 = c22 - q;
    double p2 = d0 * d0 + d1 * d1 + d2 * d2 + 2.0 * p1;
    if (p2 <= 0.0) {
      e0 = e1 = e2 = q;
    } else {
      double p = sqrt(p2 / 6.0);
      double ip = 1.0 / p;
      double b00 = d0 * ip, b11 = d1 * ip, b22 = d2 * ip;
      double b01 = c01 * ip, b02 = c02 * ip, b12 = c12 * ip;
      double det = b00 * (b11 * b22 - b12 * b12)
                 - b01 * (b01 * b22 - b12 * b02)
                 + b02 * (b01 * b12 - b11 * b02);
      double r = 0.5 * det;
      r = fmin(1.0, fmax(-1.0, r));
      double phi = acos(r) / 3.0;
      double lmax = q + 2.0 * p * cos(phi);
      double lmin = q + 2.0 * p * cos(phi + 2.0943951023931953);
      e0 = lmin; e2 = lmax; e1 = 3.0 * q - lmax - lmin;
    }
  }
  float ev0 = (float)e0, ev1 = (float)e1, ev2 = (float)e2;
  float h[4];
  #pragma unroll
  for (int o = 0; o < 4; ++o) {
    float t = ev0 * ldT(W1 + o * 3 + 0) + ev1 * ldT(W1 + o * 3 + 1)
            + ev2 * ldT(W1 + o * 3 + 2) + ldT(b1 + o);
    h[o] = fmaxf(t, 0.f);
  }
  #pragma unroll
  for (int j = 0; j < 4; ++j) {
    float t = h[0] * ldT(W2 + j * 4 + 0) + h[1] * ldT(W2 + j * 4 + 1)
            + h[2] * ldT(W2 + j * 4 + 2) + h[3] * ldT(W2 + j * 4 + 3)
            + ldT(b2 + j);
    stT(out4 + ((size_t)b * 4 + j) * NN + n, t);
    zbuf[((size_t)b * 132 + 128 + j) * NN + n] = __float2bfloat16(t);
  }
}

// ---------- conv1x1 + bias + BN + ReLU: bf16 MFMA GEMM, 64(O)x128(N) tile ----------
// 4 waves; wave (wr,wc) owns the 32x64 quadrant = 2x4 fragments of 16x16x32 MFMA
// (8 MFMA per 6 frag-loads per K-step; blocks/barriers halved vs 64x64).
// A frag = 8 contiguous C of one W row. X staged TRANSPOSED [n][c] with row-bit
// XOR swizzle col = c ^ ((n>>3 & 7)<<3) on both write and read sides.
// LDS row stride 72 elems -> conflict-free b128 frag reads (144B === 4 dw mod 32 banks).
template <class TX, class TP, class TO>
__global__ __launch_bounds__(256) void k_gemm(
    const int* __restrict__ flag, int want,
    const TX* __restrict__ X, int C,
    const TP* __restrict__ W, const TP* __restrict__ bias,
    const TP* __restrict__ bn, int O,
    TO* __restrict__ Yout, int YRo, int yoffo,
    bf16* __restrict__ Ybuf, int YRb, int yoffb) {
  if (flag && *flag != want) return;
  __shared__ __align__(16) unsigned short Ws[64][72];
  __shared__ __align__(16) unsigned short Xs[128][72];
  const int tid  = threadIdx.x;
  const int lane = tid & 63;
  const int wv   = tid >> 6;
  const int wr = wv >> 1, wc = wv & 1;
  const int l15 = lane & 15, lg = lane >> 4;
  const int nBase = blockIdx.x * 128;
  const int oBase = blockIdx.y * 64;
  const int b = blockIdx.z;
  const TX* Xb = X + (size_t)b * C * NN;

  f32x4 acc[2][4];
  #pragma unroll
  for (int m = 0; m < 2; ++m)
    #pragma unroll
    for (int n = 0; n < 4; ++n) acc[m][n] = (f32x4){0.f, 0.f, 0.f, 0.f};

  // W staging: 64x64 tile = 512 groups of 8; thread does groups {tid, tid+256}
  const int wo  = tid >> 3;            // W tile row (h=0: 0..31, h=1: +32)
  const int wc0 = (tid & 7) << 3;      // W tile col (8-elem chunk)
  // X staging: 64 c x 128 n = 1024 groups of 8; thread does 4 (h=0..3)
  const int xc  = tid >> 4;            // X tile c base (0..15), +16 per h
  const int xn0 = (tid & 15) << 3;     // X tile n0 (0..120)
  const int xswz = ((xn0 >> 3) & 7) << 3;  // row-bit swizzle for this n-octet

  for (int cb = 0; cb < C; cb += 64) {
    // ---- stage W[oBase..+63][cb..+63] -> Ws, one ds_write_b128 per group
    #pragma unroll
    for (int h = 0; h < 2; ++h) {
      const int o  = wo + h * 32;
      const int go = oBase + o, gc = cb + wc0;
      const int crem = C - gc;
      unsigned short s[8];
      if (go < O && crem >= 8) {
        ld8bits(W + (size_t)go * C + gc, s);
      } else {
        #pragma unroll
        for (int j = 0; j < 8; ++j)
          s[j] = (go < O && j < crem) ? f2us(ldT(W + (size_t)go * C + gc + j))
                                      : (unsigned short)0;
      }
      uint4 u;
      u.x = (unsigned)s[0] | ((unsigned)s[1] << 16);
      u.y = (unsigned)s[2] | ((unsigned)s[3] << 16);
      u.z = (unsigned)s[4] | ((unsigned)s[5] << 16);
      u.w = (unsigned)s[6] | ((unsigned)s[7] << 16);
      *(uint4*)&Ws[o][wc0] = u;
    }
    // ---- stage X[cb..+63][nBase..+127] transposed -> Xs[n][c ^ swz]
    #pragma unroll
    for (int h = 0; h < 4; ++h) {
      const int c  = xc + h * 16;
      const int gc = cb + c;
      unsigned short s[8];
      if (gc < C) {
        ld8bits(Xb + (size_t)gc * NN + nBase + xn0, s);
      } else {
        #pragma unroll
        for (int j = 0; j < 8; ++j) s[j] = 0;
      }
      const int xcol = c ^ xswz;
      #pragma unroll
      for (int j = 0; j < 8; ++j) Xs[xn0 + j][xcol] = s[j];  // compile-time s[j]
    }
    __syncthreads();
    #pragma unroll
    for (int kk = 0; kk < 2; ++kk) {
      bfv8 af[2], xf[4];
      #pragma unroll
      for (int m = 0; m < 2; ++m)
        af[m] = ldfrag(&Ws[wr * 32 + m * 16 + l15][kk * 32 + lg * 8]);
      #pragma unroll
      for (int n = 0; n < 4; ++n) {
        const int nl  = wc * 64 + n * 16 + l15;
        const int col = (kk * 32 + lg * 8) ^ (((nl >> 3) & 7) << 3);
        xf[n] = ldfrag(&Xs[nl][col]);
      }
      #pragma unroll
      for (int m = 0; m < 2; ++m)
        #pragma unroll
        for (int n = 0; n < 4; ++n)
          acc[m][n] = __builtin_amdgcn_mfma_f32_16x16x32_bf16(af[m], xf[n], acc[m][n], 0, 0, 0);
    }
    __syncthreads();
  }

  // ---- epilogue: C/D layout col=lane&15, row=(lane>>4)*4+reg (m89-verified)
  #pragma unroll
  for (int m = 0; m < 2; ++m) {
    const int ob = oBase + wr * 32 + m * 16 + lg * 4;
    #pragma unroll
    for (int r = 0; r < 4; ++r) {
      const int oo = ob + r;
      if (oo >= O) continue;
      const float bc  = ldT(bias + oo);
      const float g   = ldT(bn + oo);
      const float bbv = ldT(bn + O + oo);
      const float mm  = ldT(bn + 2 * O + oo);
      const float vv  = ldT(bn + 3 * O + oo);
      const float inv = g / sqrtf(vv + 1e-5f);
      const float sh  = bbv - mm * inv;
      #pragma unroll
      for (int n = 0; n < 4; ++n) {
        const int nn2 = nBase + wc * 64 + n * 16 + l15;
        const float rv = fmaxf((acc[m][n][r] + bc) * inv + sh, 0.f);
        if (Yout) stT(Yout + ((size_t)b * YRo + yoffo + oo) * NN + nn2, rv);
        if (Ybuf) Ybuf[((size_t)b * YRb + yoffb + oo) * NN + nn2] = __float2bfloat16(rv);
      }
    }
  }
}

// per-mode: prep only
template <class TI>
static void launch_prep(int want, const int* flag, void* const* d_in, void* d_out,
                        hipStream_t stream, float* xyz, float4* pts4) {
  typedef TI TO;
  const TI* pc = (const TI*)d_in[0];
  TO* out0 = (TO*)d_out;
  k_prep<TI, TO><<<dim3((BB * NN + 255) / 256), 256, 0, stream>>>(flag, want, pc, xyz, pts4, out0);
}

// per-mode: everything after KNN's idx is available
template <class TI>
static void launch_rest(int want, const int* flag,
                        void* const* d_in, void* d_out, hipStream_t stream,
                        float* xyz, int* idx,
                        bf16* t512, bf16* t256, bf16* t64, bf16* fbuf, bf16* zbuf) {
  typedef TI TO;
  const TI* h1    = (const TI*)d_in[1];
  const TI* h2    = (const TI*)d_in[2];
  const TI* W_dg1 = (const TI*)d_in[3];  const TI* b_dg1 = (const TI*)d_in[4];  const TI* bn_dg1 = (const TI*)d_in[5];
  const TI* W_dg2 = (const TI*)d_in[6];  const TI* b_dg2 = (const TI*)d_in[7];  const TI* bn_dg2 = (const TI*)d_in[8];
  const TI* W_dg3 = (const TI*)d_in[9];  const TI* b_dg3 = (const TI*)d_in[10]; const TI* bn_dg3 = (const TI*)d_in[11];
  const TI* W_c1  = (const TI*)d_in[12]; const TI* b_c1  = (const TI*)d_in[13]; const TI* bn_c1  = (const TI*)d_in[14];
  const TI* W_c2  = (const TI*)d_in[15]; const TI* b_c2  = (const TI*)d_in[16]; const TI* bn_c2  = (const TI*)d_in[17];
  const TI* W_c3  = (const TI*)d_in[18]; const TI* b_c3  = (const TI*)d_in[19]; const TI* bn_c3  = (const TI*)d_in[20];
  const TI* W_f   = (const TI*)d_in[21]; const TI* b_f   = (const TI*)d_in[22]; const TI* bn_f   = (const TI*)d_in[23];
  const TI* W_ed1 = (const TI*)d_in[24]; const TI* b_ed1 = (const TI*)d_in[25];
  const TI* W_ed2 = (const TI*)d_in[26]; const TI* b_ed2 = (const TI*)d_in[27];

  TO* out  = (TO*)d_out;
  TO* out1 = out + 49152;
  TO* out2 = out1 + 2097152;
  TO* out3 = out2 + 2097152;
  TO* out4 = out3 + 524288;

  dim3 blk(256);
  k_h1<TI, TO><<<dim3((BB * 128 * NN / 8 + 255) / 256), 256, 0, stream>>>(flag, want, h1, out2, fbuf);
  // dg chain
  k_gemm<TI, TI, TO><<<dim3(32, 4, BB), blk, 0, stream>>>(flag, want, h2, 1024, W_dg1, b_dg1, bn_dg1, 256,
                                                          (TO*)nullptr, 0, 0, t256, 256, 0);
  k_gemm<bf16, TI, TO><<<dim3(32, 1, BB), blk, 0, stream>>>(flag, want, t256, 256, W_dg2, b_dg2, bn_dg2, 64,
                                                            (TO*)nullptr, 0, 0, t64, 64, 0);
  k_gemm<bf16, TI, TO><<<dim3(32, 1, BB), blk, 0, stream>>>(flag, want, t64, 64, W_dg3, b_dg3, bn_dg3, 32,
                                                            out3, 32, 0, fbuf, 160, 128);
  // c chain
  k_gemm<bf16, TI, TO><<<dim3(32, 8, BB), blk, 0, stream>>>(flag, want, fbuf, 160, W_c1, b_c1, bn_c1, 512,
                                                            (TO*)nullptr, 0, 0, t512, 512, 0);
  k_ef<TI, TO><<<dim3((BB * NN + 255) / 256), 256, 0, stream>>>(flag, want, xyz, idx, W_ed1, b_ed1, W_ed2, b_ed2, out4, zbuf);
  k_gemm<bf16, TI, TO><<<dim3(32, 4, BB), blk, 0, stream>>>(flag, want, t512, 512, W_c2, b_c2, bn_c2, 256,
                                                            (TO*)nullptr, 0, 0, t256, 256, 0);
  k_gemm<bf16, TI, TO><<<dim3(32, 2, BB), blk, 0, stream>>>(flag, want, t256, 256, W_c3, b_c3, bn_c3, 128,
                                                            (TO*)nullptr, 0, 0, zbuf, 132, 0);
  k_gemm<bf16, TI, TO><<<dim3(32, 2, BB), blk, 0, stream>>>(flag, want, zbuf, 132, W_f, b_f, bn_f, 128,
                                                            out1, 128, 0, (bf16*)nullptr, 0, 0);
}

extern "C" void kernel_launch(void* const* d_in, const int* in_sizes, int n_in,
                              void* d_out, int out_size, void* d_ws, size_t ws_size,
                              hipStream_t stream) {
  char* ws = (char*)d_ws;
  int*    flag = (int*)(ws + 0);
  float*  xyz  = (float*)(ws + 1024);       // 196608 B
  int*    idx  = (int*)(ws + 328704);       // 655360 B
  bf16*   t512 = (bf16*)(ws + 1048576);     // 16777216 B
  bf16*   t256 = (bf16*)(ws + 17825792);    // 8388608 B
  bf16*   t64  = (bf16*)(ws + 26214400);    // 2097152 B
  bf16*   fbuf = (bf16*)(ws + 28311552);    // 5242880 B
  bf16*   zbuf = (bf16*)(ws + 33554432);    // 4325376 B -> end ~36.1 MB
  // pts4 aliases t512: k_knn (its only reader) completes before the c1 GEMM
  // (t512's producer) launches on the same stream.
  float4* pts4 = (float4*)(ws + 1048576);   // 262144 B

  // host-side dtype detection from byte sizes; sniffer fallback if inconclusive
  int mode = -1;
  if (in_sizes) {
    if (in_sizes[0] == (int)(BB * NN * 3 * sizeof(float))) mode = 0;
    else if (in_sizes[0] == (int)(BB * NN * 3 * sizeof(bf16))) mode = 1;
  }

  if (mode < 0) {
    k_sniff<<<1, 64, 0, stream>>>((const unsigned int*)d_in[0], flag);
    launch_prep<float>(0, flag, d_in, d_out, stream, xyz, pts4);
    launch_prep<bf16>(1, flag, d_in, d_out, stream, xyz, pts4);
  } else if (mode == 0) {
    launch_prep<float>(0, nullptr, d_in, d_out, stream, xyz, pts4);
  } else {
    launch_prep<bf16>(1, nullptr, d_in, d_out, stream, xyz, pts4);
  }

  k_knn<<<dim3(NN / KQ, BB), 256, 0, stream>>>(pts4, idx);

  if (mode != 1) launch_rest<float>(0, mode < 0 ? flag : nullptr, d_in, d_out, stream,
                                    xyz, idx, t512, t256, t64, fbuf, zbuf);
  if (mode != 0) launch_rest<bf16>(1, mode < 0 ? flag : nullptr, d_in, d_out, stream,
                                   xyz, idx, t512, t256, t64, fbuf, zbuf);
}

// Round 12
// 386.828 us; speedup vs baseline: 1.0498x; 1.0498x over previous
//
#include <hip/hip_runtime.h>
#include <hip/hip_bf16.h>
#include <math.h>

typedef __hip_bfloat16 bf16;

#define BB 4
#define NN 4096
#define KNB 10
#define KQ 16            // queries per KNN block (held in pinned VGPRs)
#define KCAP 64          // survivor capacity per query

typedef __bf16 bfv8 __attribute__((ext_vector_type(8)));
typedef float  f32x4 __attribute__((ext_vector_type(4)));

__device__ __forceinline__ float ldT(const float* p) { return *p; }
__device__ __forceinline__ float ldT(const bf16* p)  { return __bfloat162float(*p); }
__device__ __forceinline__ void  stT(float* p, float v) { *p = v; }
__device__ __forceinline__ void  stT(bf16* p,  float v) { *p = __float2bfloat16(v); }

__device__ __forceinline__ unsigned short f2us(float x) {
  union { bf16 h; unsigned short u; } cv;
  cv.h = __float2bfloat16(x);
  return cv.u;
}

// load 8 consecutive elements as bf16 bit patterns (vector fast path)
__device__ __forceinline__ void ld8bits(const float* p, unsigned short* s) {
  const float4 a = *(const float4*)p;
  const float4 b = *(const float4*)(p + 4);
  s[0] = f2us(a.x); s[1] = f2us(a.y); s[2] = f2us(a.z); s[3] = f2us(a.w);
  s[4] = f2us(b.x); s[5] = f2us(b.y); s[6] = f2us(b.z); s[7] = f2us(b.w);
}
__device__ __forceinline__ void ld8bits(const bf16* p, unsigned short* s) {
  const uint2 a = *(const uint2*)p;        // 8B-aligned for all row strides used here
  const uint2 b = *(const uint2*)(p + 4);
  s[0] = a.x & 0xffff; s[1] = a.x >> 16; s[2] = a.y & 0xffff; s[3] = a.y >> 16;
  s[4] = b.x & 0xffff; s[5] = b.x >> 16; s[6] = b.y & 0xffff; s[7] = b.y >> 16;
}

__device__ __forceinline__ bfv8 ldfrag(const unsigned short* p) {
  union { uint4 u; bfv8 v; } t;
  t.u = *(const uint4*)p;
  return t.v;
}

// ---------- dtype sniffer (fallback when in_sizes is inconclusive) ----------
__global__ void k_sniff(const unsigned int* __restrict__ pcw, int* __restrict__ flag) {
  if (blockIdx.x == 0 && threadIdx.x == 0) {
    int hits = 0;
    for (int i = 0; i < 64; ++i) {
      unsigned int e = (pcw[i] >> 7) & 0xFF;
      if (e >= 100 && e <= 140) ++hits;
    }
    *flag = (hits >= 40) ? 1 : 0;   // 1 = bf16 I/O, 0 = fp32 I/O
  }
}

// ---------- prep: xyz fp32 + packed {x,y,z,norm} + out0 copy ----------
template <class TI, class TO>
__global__ void k_prep(const int* __restrict__ flag, int want,
                       const TI* __restrict__ pc, float* __restrict__ xyz,
                       float4* __restrict__ pts4, TO* __restrict__ out0) {
  if (flag && *flag != want) return;
  int i = blockIdx.x * blockDim.x + threadIdx.x;
  if (i >= BB * NN) return;
  float x = ldT(pc + i * 3 + 0), y = ldT(pc + i * 3 + 1), z = ldT(pc + i * 3 + 2);
  xyz[i * 3 + 0] = x; xyz[i * 3 + 1] = y; xyz[i * 3 + 2] = z;
  // norm with the same fmaf chain k_knn uses -> identical distances
  const float nrm = fmaf(x, x, fmaf(y, y, z * z));
  pts4[i] = make_float4(x, y, z, nrm);
  stT(out0 + i * 3 + 0, x); stT(out0 + i * 3 + 1, y); stT(out0 + i * 3 + 2, z);
}

// ---------- h1 -> out2 copy + fbuf rows 0..127, vectorized 8 elems/thread ----------
// bf16 mode: pure bit-copies (uint4 in, 2x uint4 out). fp32 mode: 2x float4 in,
// 2x float4 out + packed bf16 uint4. (G13: scalar bf16 loads are 2-2.5x slower.)
template <class TI, class TO>
__global__ void k_h1(const int* __restrict__ flag, int want,
                     const TI* __restrict__ h1, TO* __restrict__ out2,
                     bf16* __restrict__ fbuf) {
  if (flag && *flag != want) return;
  const int per8 = 128 * NN / 8;               // 8-elem groups per batch
  int g = blockIdx.x * blockDim.x + threadIdx.x;
  if (g >= BB * per8) return;
  const int b = g / per8;
  const int e = (g - b * per8) * 8;            // element offset within batch
  const size_t src = (size_t)b * (128 * NN) + e;
  bf16* fb = fbuf + (size_t)b * 160 * NN + e;
  if constexpr (sizeof(TI) == 2) {
    const uint4 u = *(const uint4*)(h1 + src);
    *(uint4*)(out2 + src) = u;
    *(uint4*)fb = u;
  } else {
    const float4 a = *(const float4*)(h1 + src);
    const float4 c = *(const float4*)(h1 + src + 4);
    *(float4*)(out2 + src) = a;
    *(float4*)(out2 + src + 4) = c;
    uint4 u;
    u.x = (unsigned)f2us(a.x) | ((unsigned)f2us(a.y) << 16);
    u.y = (unsigned)f2us(a.z) | ((unsigned)f2us(a.w) << 16);
    u.z = (unsigned)f2us(c.x) | ((unsigned)f2us(c.y) << 16);
    u.w = (unsigned)f2us(c.z) | ((unsigned)f2us(c.w) << 16);
    *(uint4*)fb = u;
  }
}

// ---------- KNN v11 (R9 best, unchanged): candidate-major, 16 queries pinned ----------
__global__ __launch_bounds__(256, 4) void k_knn(const float4* __restrict__ pts4,
                                                int* __restrict__ idxout) {
  __shared__ float smin[256][KQ + 1];   // stride 17 dw: 2 lanes/bank = free
  __shared__ float stau[KQ];
  __shared__ float sd[KQ][KCAP];
  __shared__ int   si[KQ][KCAP];
  __shared__ unsigned int scnt[KQ];
  const int tid = threadIdx.x;
  const int b = blockIdx.y;
  const int nBase = blockIdx.x * KQ;
  const float4* pb = pts4 + (size_t)b * NN;
  if (tid < KQ) scnt[tid] = 0u;

  // query coords: global -> registers, PINNED so the compiler can't sink them
  float qx[KQ], qy[KQ], qz[KQ], qn[KQ];
  #pragma unroll
  for (int q = 0; q < KQ; ++q) {
    const float4 p = pb[nBase + q];
    qx[q] = p.x; qy[q] = p.y; qz[q] = p.z; qn[q] = p.w;
  }
  #pragma unroll
  for (int q = 0; q < KQ; ++q)
    asm volatile("" : "+v"(qx[q]), "+v"(qy[q]), "+v"(qz[q]), "+v"(qn[q]));

  // ---- phase 1: per-thread min over 16 coalesced candidates x 16 queries
  float mv[KQ];
  #pragma unroll
  for (int q = 0; q < KQ; ++q) mv[q] = 1e30f;
  {
    float4 cA = pb[tid];
    #pragma unroll
    for (int it = 0; it < 16; ++it) {
      const float4 cB = (it + 1 < 16) ? pb[(it + 1) * 256 + tid] : cA;  // 2-deep prefetch
      #pragma unroll
      for (int q = 0; q < KQ; ++q) {
        const float dot = fmaf(qx[q], cA.x, fmaf(qy[q], cA.y, qz[q] * cA.z));
        const float d = (qn[q] + cA.w) - 2.0f * dot;
        mv[q] = fminf(mv[q], d);
      }
      cA = cB;
    }
  }
  #pragma unroll
  for (int q = 0; q < KQ; ++q) smin[tid][q] = mv[q];
  __syncthreads();

  // ---- tau: thread q scans the 256 minima for query q, keeps 10 smallest
  if (tid < KQ) {
    float arr[KNB];
    #pragma unroll
    for (int t = 0; t < KNB; ++t) arr[t] = 1e30f;
    for (int t = 0; t < 256; ++t) {
      const float v = smin[t][tid];
      if (v < arr[KNB - 1]) {
        arr[KNB - 1] = v;
        #pragma unroll
        for (int u = KNB - 1; u > 0; --u)
          if (arr[u] < arr[u - 1]) { const float tm = arr[u]; arr[u] = arr[u - 1]; arr[u - 1] = tm; }
      }
    }
    stau[tid] = arr[KNB - 1];
  }
  __syncthreads();
  float tq[KQ];
  #pragma unroll
  for (int q = 0; q < KQ; ++q) tq[q] = stau[q];

  // ---- phase 2: rescan (L1-hot), filter, push survivors
  {
    float4 cA = pb[tid];
    #pragma unroll
    for (int it = 0; it < 16; ++it) {
      const float4 cB = (it + 1 < 16) ? pb[(it + 1) * 256 + tid] : cA;
      const int j = it * 256 + tid;
      #pragma unroll
      for (int q = 0; q < KQ; ++q) {
        const float dot = fmaf(qx[q], cA.x, fmaf(qy[q], cA.y, qz[q] * cA.z));
        const float d = (qn[q] + cA.w) - 2.0f * dot;
        if (d <= tq[q]) {
          const unsigned int pos = atomicAdd(&scnt[q], 1u);
          if (pos < KCAP) { sd[q][pos] = d; si[q][pos] = j; }
        }
      }
      cA = cB;
    }
  }
  __syncthreads();

  // ---- phase 3: exact lex (d, idx) top-10 over survivors; thread q = query q
  if (tid < KQ) {
    const int qq = tid;
    const int nq = nBase + qq;
    int* op = idxout + ((size_t)b * NN + nq) * KNB;
    const unsigned int m = scnt[qq];
    float dk[KNB]; int ik[KNB];
    #pragma unroll
    for (int t = 0; t < KNB; ++t) { dk[t] = 1e30f; ik[t] = NN; }
    if (m <= KCAP) {
      for (unsigned int e = 0; e < m; ++e) {
        const float d = sd[qq][e];
        const int j = si[qq][e];
        if (d < dk[KNB - 1] || (d == dk[KNB - 1] && j < ik[KNB - 1])) {
          dk[KNB - 1] = d; ik[KNB - 1] = j;
          #pragma unroll
          for (int t = KNB - 1; t > 0; --t) {
            if (dk[t] < dk[t - 1] || (dk[t] == dk[t - 1] && ik[t] < ik[t - 1])) {
              const float td = dk[t]; dk[t] = dk[t - 1]; dk[t - 1] = td;
              const int ti = ik[t]; ik[t] = ik[t - 1]; ik[t - 1] = ti;
            }
          }
        }
      }
    } else {
      // exact serial fallback (correctness insurance; never taken for random data)
      const float4 pQ = pb[nq];
      for (int j = 0; j < NN; ++j) {
        const float4 c = pb[j];
        const float dot = fmaf(pQ.x, c.x, fmaf(pQ.y, c.y, pQ.z * c.z));
        const float d = (pQ.w + c.w) - 2.0f * dot;
        if (d < dk[KNB - 1] || (d == dk[KNB - 1] && j < ik[KNB - 1])) {
          dk[KNB - 1] = d; ik[KNB - 1] = j;
          #pragma unroll
          for (int t = KNB - 1; t > 0; --t) {
            if (dk[t] < dk[t - 1] || (dk[t] == dk[t - 1] && ik[t] < ik[t - 1])) {
              const float td = dk[t]; dk[t] = dk[t - 1]; dk[t - 1] = td;
              const int ti = ik[t]; ik[t] = ik[t - 1]; ik[t - 1] = ti;
            }
          }
        }
      }
    }
    #pragma unroll
    for (int t = 0; t < KNB; ++t) op[t] = ik[t];
  }
}

// ---------- eigen features ----------
template <class TP, class TO>
__global__ void k_ef(const int* __restrict__ flag, int want,
                     const float* __restrict__ xyz, const int* __restrict__ idxin,
                     const TP* __restrict__ W1, const TP* __restrict__ b1,
                     const TP* __restrict__ W2, const TP* __restrict__ b2,
                     TO* __restrict__ out4, bf16* __restrict__ zbuf) {
  if (flag && *flag != want) return;
  int i = blockIdx.x * blockDim.x + threadIdx.x;
  if (i >= BB * NN) return;
  int b = i / NN, n = i - b * NN;
  const float* xb = xyz + (size_t)b * NN * 3;
  const int* id = idxin + (size_t)i * KNB;
  double px[KNB], py[KNB], pz[KNB];
  double mx = 0, my = 0, mz = 0;
  #pragma unroll
  for (int k = 0; k < KNB; ++k) {
    int j = id[k];
    px[k] = (double)xb[j * 3 + 0];
    py[k] = (double)xb[j * 3 + 1];
    pz[k] = (double)xb[j * 3 + 2];
    mx += px[k]; my += py[k]; mz += pz[k];
  }
  mx /= KNB; my /= KNB; mz /= KNB;
  double c00 = 0, c01 = 0, c02 = 0, c11 = 0, c12 = 0, c22 = 0;
  #pragma unroll
  for (int k = 0; k < KNB; ++k) {
    double dx = px[k] - mx, dy = py[k] - my, dz = pz[k] - mz;
    c00 += dx * dx; c01 += dx * dy; c02 += dx * dz;
    c11 += dy * dy; c12 += dy * dz; c22 += dz * dz;
  }
  c00 /= KNB; c01 /= KNB; c02 /= KNB; c11 /= KNB; c12 /= KNB; c22 /= KNB;
  double e0, e1, e2;
  {
    double p1 = c01 * c01 + c02 * c02 + c12 * c12;
    double q = (c00 + c11 + c22) / 3.0;
    double d0 = c00 - q, d1 = c11 - q, d2 = c22 - q;
    double p2 = d0 * d0 + d1 * d1 + d2 * d2 + 2.0 * p1;
    if (p2 <= 0.0) {
      e0 = e1 = e2 = q;
    } else {
      double p = sqrt(p2 / 6.0);
      double ip = 1.0 / p;
      double b00 = d0 * ip, b11 = d1 * ip, b22 = d2 * ip;
      double b01 = c01 * ip, b02 = c02 * ip, b12 = c12 * ip;
      double det = b00 * (b11 * b22 - b12 * b12)
                 - b01 * (b01 * b22 - b12 * b02)
                 + b02 * (b01 * b12 - b11 * b02);
      double r = 0.5 * det;
      r = fmin(1.0, fmax(-1.0, r));
      double phi = acos(r) / 3.0;
      double lmax = q + 2.0 * p * cos(phi);
      double lmin = q + 2.0 * p * cos(phi + 2.0943951023931953);
      e0 = lmin; e2 = lmax; e1 = 3.0 * q - lmax - lmin;
    }
  }
  float ev0 = (float)e0, ev1 = (float)e1, ev2 = (float)e2;
  float h[4];
  #pragma unroll
  for (int o = 0; o < 4; ++o) {
    float t = ev0 * ldT(W1 + o * 3 + 0) + ev1 * ldT(W1 + o * 3 + 1)
            + ev2 * ldT(W1 + o * 3 + 2) + ldT(b1 + o);
    h[o] = fmaxf(t, 0.f);
  }
  #pragma unroll
  for (int j = 0; j < 4; ++j) {
    float t = h[0] * ldT(W2 + j * 4 + 0) + h[1] * ldT(W2 + j * 4 + 1)
            + h[2] * ldT(W2 + j * 4 + 2) + h[3] * ldT(W2 + j * 4 + 3)
            + ldT(b2 + j);
    stT(out4 + ((size_t)b * 4 + j) * NN + n, t);
    zbuf[((size_t)b * 132 + 128 + j) * NN + n] = __float2bfloat16(t);
  }
}

// ---------- conv1x1 + bias + BN + ReLU: bf16 MFMA GEMM (R9 64x64 tile, restored) ----------
// Y[O][N] = W[O][C] * X[C][N] per batch. 64x64 output tile, BK=64.
// 4 waves; wave (wr,wc) owns the 32x32 quadrant, 2x2 fragments of 16x16x32 MFMA.
// A frag = 8 contiguous C of one W row (m92-verified contiguous-8 layout).
// B frag = 8 contiguous C of one X column -> X staged TRANSPOSED [n][c] in LDS.
// LDS row stride 72 elems (144B = 36 dw === 4 mod 32 banks) -> conflict-free b128 frag reads.
// Xs chunk-XOR swizzle (col = c ^ n0) keeps transpose scatter-writes <=2-way (free).
// NOTE: 64x128 tile variant (R10) REGRESSED +19us total: halving the grid starves
// the small layers (O<=512) of blocks; block count is the scarce resource here.
template <class TX, class TP, class TO>
__global__ __launch_bounds__(256) void k_gemm(
    const int* __restrict__ flag, int want,
    const TX* __restrict__ X, int C,
    const TP* __restrict__ W, const TP* __restrict__ bias,
    const TP* __restrict__ bn, int O,
    TO* __restrict__ Yout, int YRo, int yoffo,
    bf16* __restrict__ Ybuf, int YRb, int yoffb) {
  if (flag && *flag != want) return;
  __shared__ __align__(16) unsigned short Ws[64][72];
  __shared__ __align__(16) unsigned short Xs[64][72];
  const int tid  = threadIdx.x;
  const int lane = tid & 63;
  const int wv   = tid >> 6;
  const int wr = wv >> 1, wc = wv & 1;
  const int l15 = lane & 15, lg = lane >> 4;
  const int nBase = blockIdx.x * 64;
  const int oBase = blockIdx.y * 64;
  const int b = blockIdx.z;
  const TX* Xb = X + (size_t)b * C * NN;

  f32x4 acc[2][2];
  #pragma unroll
  for (int m = 0; m < 2; ++m)
    #pragma unroll
    for (int n = 0; n < 2; ++n) acc[m][n] = (f32x4){0.f, 0.f, 0.f, 0.f};

  // staging work split: 512 groups of 8 elems, thread does groups {tid, tid+256}
  const int wo  = tid >> 3;            // W tile row (h=0: 0..31, h=1: +32)
  const int wc0 = (tid & 7) << 3;      // W tile col (8-elem chunk)
  const int xc  = tid >> 3;            // X tile c   (h=0: 0..31, h=1: +32)
  const int xn0 = (tid & 7) << 3;      // X tile n0; also the XOR swizzle value

  for (int cb = 0; cb < C; cb += 64) {
    // ---- stage W[oBase..+63][cb..+63] -> Ws, one ds_write_b128 per group
    #pragma unroll
    for (int h = 0; h < 2; ++h) {
      const int o  = wo + h * 32;
      const int go = oBase + o, gc = cb + wc0;
      const int crem = C - gc;
      unsigned short s[8];
      if (go < O && crem >= 8) {
        ld8bits(W + (size_t)go * C + gc, s);
      } else {
        #pragma unroll
        for (int j = 0; j < 8; ++j)
          s[j] = (go < O && j < crem) ? f2us(ldT(W + (size_t)go * C + gc + j))
                                      : (unsigned short)0;
      }
      uint4 u;
      u.x = (unsigned)s[0] | ((unsigned)s[1] << 16);
      u.y = (unsigned)s[2] | ((unsigned)s[3] << 16);
      u.z = (unsigned)s[4] | ((unsigned)s[5] << 16);
      u.w = (unsigned)s[6] | ((unsigned)s[7] << 16);
      *(uint4*)&Ws[o][wc0] = u;
    }
    // ---- stage X[cb..+63][nBase..+63] transposed -> Xs[n][c ^ n0]
    #pragma unroll
    for (int h = 0; h < 2; ++h) {
      const int c  = xc + h * 32;
      const int gc = cb + c;
      unsigned short s[8];
      if (gc < C) {
        ld8bits(Xb + (size_t)gc * NN + nBase + xn0, s);
      } else {
        #pragma unroll
        for (int j = 0; j < 8; ++j) s[j] = 0;
      }
      const int xcol = c ^ xn0;        // n0>>3 == tid&7, so 8*((n0>>3)&7) == xn0
      #pragma unroll
      for (int j = 0; j < 8; ++j) Xs[xn0 + j][xcol] = s[j];  // compile-time s[j]
    }
    __syncthreads();
    #pragma unroll
    for (int kk = 0; kk < 2; ++kk) {
      bfv8 af[2], xf[2];
      #pragma unroll
      for (int m = 0; m < 2; ++m)
        af[m] = ldfrag(&Ws[wr * 32 + m * 16 + l15][kk * 32 + lg * 8]);
      #pragma unroll
      for (int n = 0; n < 2; ++n) {
        const int nl  = wc * 32 + n * 16 + l15;
        const int col = (kk * 32 + lg * 8) ^ (((nl >> 3) & 7) << 3);
        xf[n] = ldfrag(&Xs[nl][col]);
      }
      #pragma unroll
      for (int m = 0; m < 2; ++m)
        #pragma unroll
        for (int n = 0; n < 2; ++n)
          acc[m][n] = __builtin_amdgcn_mfma_f32_16x16x32_bf16(af[m], xf[n], acc[m][n], 0, 0, 0);
    }
    __syncthreads();
  }

  // ---- epilogue: C/D layout col=lane&15, row=(lane>>4)*4+reg (m89-verified)
  #pragma unroll
  for (int m = 0; m < 2; ++m) {
    const int ob = oBase + wr * 32 + m * 16 + lg * 4;
    #pragma unroll
    for (int r = 0; r < 4; ++r) {
      const int oo = ob + r;
      if (oo >= O) continue;
      const float bc  = ldT(bias + oo);
      const float g   = ldT(bn + oo);
      const float bbv = ldT(bn + O + oo);
      const float mm  = ldT(bn + 2 * O + oo);
      const float vv  = ldT(bn + 3 * O + oo);
      const float inv = g / sqrtf(vv + 1e-5f);
      const float sh  = bbv - mm * inv;
      #pragma unroll
      for (int n = 0; n < 2; ++n) {
        const int nn2 = nBase + wc * 32 + n * 16 + l15;
        const float rv = fmaxf((acc[m][n][r] + bc) * inv + sh, 0.f);
        if (Yout) stT(Yout + ((size_t)b * YRo + yoffo + oo) * NN + nn2, rv);
        if (Ybuf) Ybuf[((size_t)b * YRb + yoffb + oo) * NN + nn2] = __float2bfloat16(rv);
      }
    }
  }
}

// per-mode: prep only
template <class TI>
static void launch_prep(int want, const int* flag, void* const* d_in, void* d_out,
                        hipStream_t stream, float* xyz, float4* pts4) {
  typedef TI TO;
  const TI* pc = (const TI*)d_in[0];
  TO* out0 = (TO*)d_out;
  k_prep<TI, TO><<<dim3((BB * NN + 255) / 256), 256, 0, stream>>>(flag, want, pc, xyz, pts4, out0);
}

// per-mode: everything after KNN's idx is available
template <class TI>
static void launch_rest(int want, const int* flag,
                        void* const* d_in, void* d_out, hipStream_t stream,
                        float* xyz, int* idx,
                        bf16* t512, bf16* t256, bf16* t64, bf16* fbuf, bf16* zbuf) {
  typedef TI TO;
  const TI* h1    = (const TI*)d_in[1];
  const TI* h2    = (const TI*)d_in[2];
  const TI* W_dg1 = (const TI*)d_in[3];  const TI* b_dg1 = (const TI*)d_in[4];  const TI* bn_dg1 = (const TI*)d_in[5];
  const TI* W_dg2 = (const TI*)d_in[6];  const TI* b_dg2 = (const TI*)d_in[7];  const TI* bn_dg2 = (const TI*)d_in[8];
  const TI* W_dg3 = (const TI*)d_in[9];  const TI* b_dg3 = (const TI*)d_in[10]; const TI* bn_dg3 = (const TI*)d_in[11];
  const TI* W_c1  = (const TI*)d_in[12]; const TI* b_c1  = (const TI*)d_in[13]; const TI* bn_c1  = (const TI*)d_in[14];
  const TI* W_c2  = (const TI*)d_in[15]; const TI* b_c2  = (const TI*)d_in[16]; const TI* bn_c2  = (const TI*)d_in[17];
  const TI* W_c3  = (const TI*)d_in[18]; const TI* b_c3  = (const TI*)d_in[19]; const TI* bn_c3  = (const TI*)d_in[20];
  const TI* W_f   = (const TI*)d_in[21]; const TI* b_f   = (const TI*)d_in[22]; const TI* bn_f   = (const TI*)d_in[23];
  const TI* W_ed1 = (const TI*)d_in[24]; const TI* b_ed1 = (const TI*)d_in[25];
  const TI* W_ed2 = (const TI*)d_in[26]; const TI* b_ed2 = (const TI*)d_in[27];

  TO* out  = (TO*)d_out;
  TO* out1 = out + 49152;
  TO* out2 = out1 + 2097152;
  TO* out3 = out2 + 2097152;
  TO* out4 = out3 + 524288;

  dim3 blk(256);
  k_h1<TI, TO><<<dim3((BB * 128 * NN / 8 + 255) / 256), 256, 0, stream>>>(flag, want, h1, out2, fbuf);
  // dg chain
  k_gemm<TI, TI, TO><<<dim3(64, 4, BB), blk, 0, stream>>>(flag, want, h2, 1024, W_dg1, b_dg1, bn_dg1, 256,
                                                          (TO*)nullptr, 0, 0, t256, 256, 0);
  k_gemm<bf16, TI, TO><<<dim3(64, 1, BB), blk, 0, stream>>>(flag, want, t256, 256, W_dg2, b_dg2, bn_dg2, 64,
                                                            (TO*)nullptr, 0, 0, t64, 64, 0);
  k_gemm<bf16, TI, TO><<<dim3(64, 1, BB), blk, 0, stream>>>(flag, want, t64, 64, W_dg3, b_dg3, bn_dg3, 32,
                                                            out3, 32, 0, fbuf, 160, 128);
  // c chain
  k_gemm<bf16, TI, TO><<<dim3(64, 8, BB), blk, 0, stream>>>(flag, want, fbuf, 160, W_c1, b_c1, bn_c1, 512,
                                                            (TO*)nullptr, 0, 0, t512, 512, 0);
  k_ef<TI, TO><<<dim3((BB * NN + 255) / 256), 256, 0, stream>>>(flag, want, xyz, idx, W_ed1, b_ed1, W_ed2, b_ed2, out4, zbuf);
  k_gemm<bf16, TI, TO><<<dim3(64, 4, BB), blk, 0, stream>>>(flag, want, t512, 512, W_c2, b_c2, bn_c2, 256,
                                                            (TO*)nullptr, 0, 0, t256, 256, 0);
  k_gemm<bf16, TI, TO><<<dim3(64, 2, BB), blk, 0, stream>>>(flag, want, t256, 256, W_c3, b_c3, bn_c3, 128,
                                                            (TO*)nullptr, 0, 0, zbuf, 132, 0);
  k_gemm<bf16, TI, TO><<<dim3(64, 2, BB), blk, 0, stream>>>(flag, want, zbuf, 132, W_f, b_f, bn_f, 128,
                                                            out1, 128, 0, (bf16*)nullptr, 0, 0);
}

extern "C" void kernel_launch(void* const* d_in, const int* in_sizes, int n_in,
                              void* d_out, int out_size, void* d_ws, size_t ws_size,
                              hipStream_t stream) {
  char* ws = (char*)d_ws;
  int*    flag = (int*)(ws + 0);
  float*  xyz  = (float*)(ws + 1024);       // 196608 B
  int*    idx  = (int*)(ws + 328704);       // 655360 B
  bf16*   t512 = (bf16*)(ws + 1048576);     // 16777216 B
  bf16*   t256 = (bf16*)(ws + 17825792);    // 8388608 B
  bf16*   t64  = (bf16*)(ws + 26214400);    // 2097152 B
  bf16*   fbuf = (bf16*)(ws + 28311552);    // 5242880 B
  bf16*   zbuf = (bf16*)(ws + 33554432);    // 4325376 B -> end ~36.1 MB
  // pts4 aliases t512: k_knn (its only reader) completes before the c1 GEMM
  // (t512's producer) launches on the same stream.
  float4* pts4 = (float4*)(ws + 1048576);   // 262144 B

  // host-side dtype detection from byte sizes; sniffer fallback if inconclusive
  int mode = -1;
  if (in_sizes) {
    if (in_sizes[0] == (int)(BB * NN * 3 * sizeof(float))) mode = 0;
    else if (in_sizes[0] == (int)(BB * NN * 3 * sizeof(bf16))) mode = 1;
  }

  if (mode < 0) {
    k_sniff<<<1, 64, 0, stream>>>((const unsigned int*)d_in[0], flag);
    launch_prep<float>(0, flag, d_in, d_out, stream, xyz, pts4);
    launch_prep<bf16>(1, flag, d_in, d_out, stream, xyz, pts4);
  } else if (mode == 0) {
    launch_prep<float>(0, nullptr, d_in, d_out, stream, xyz, pts4);
  } else {
    launch_prep<bf16>(1, nullptr, d_in, d_out, stream, xyz, pts4);
  }

  k_knn<<<dim3(NN / KQ, BB), 256, 0, stream>>>(pts4, idx);

  if (mode != 1) launch_rest<float>(0, mode < 0 ? flag : nullptr, d_in, d_out, stream,
                                    xyz, idx, t512, t256, t64, fbuf, zbuf);
  if (mode != 0) launch_rest<bf16>(1, mode < 0 ? flag : nullptr, d_in, d_out, stream,
                                   xyz, idx, t512, t256, t64, fbuf, zbuf);
}